// Round 5
// baseline (7256.130 us; speedup 1.0000x reference)
//
#include <hip/hip_runtime.h>
#include <math.h>

// ---------------------------------------------------------------------------
// TensorProcessor: conv3d(1,3,1)+bias+relu -> Tucker-HOOI core (8,6,6,6)
// Round 10 (resubmit; round-4 bench was a container-infra failure).
// Producer-precomputed Householder: the pivot wave (row t) computes
// alpha/xnorm2/beta/tau/scl at the END of the previous step and publishes the
// column PRE-SCALED with boundary selects applied (ulb) + scalars
// (taus/scls/ee). Consumers per step: read ul seg (4xb128) + tau + u_row,
// symv 16 fma + DPP oct reduce, publish w_pre/pu, barrier, 48-fma update.
// Removes ~110 VALU ops/thread/step and takes sqrt/rcp off the global
// critical path. oct_sum all-DPP (row_half_mirror). Other phases unchanged.
// ---------------------------------------------------------------------------

// ws layout (float offsets)
constexpr long long OFF_T   = 0LL;                 // 26,214,400
constexpr long long OFF_TC  = 26214400LL;          // 6,553,600
constexpr long long OFF_TB  = 32768000LL;          // 1,572,864
constexpr long long OFF_PART= OFF_TC;              // 240*16384 (init only)
constexpr long long OFF_TD0a= OFF_TC;              // mode0 (32,6,6,64)=73,728
constexpr long long OFF_TD0b= OFF_TC + 131072;     // mode0 (32,6,6,6)=6,912
constexpr long long OFF_TD  = OFF_TB + 1000000LL;  // sweep small tensors
constexpr long long OFF_G0  = OFF_TB + 1400000LL;  // 1,024
constexpr long long OFF_G1  = OFF_G0 + 1024;       // 10,000
constexpr long long OFF_G2  = OFF_G1 + 10000;      // 16,384
constexpr long long OFF_G3  = OFF_G2 + 16384;      // 4,096
constexpr long long OFF_F0  = 34340864LL;          // 256
constexpr long long OFF_F1  = OFF_F0 + 256;        // 600
constexpr long long OFF_F2  = OFF_F1 + 600;        // 768
constexpr long long OFF_F3  = OFF_F2 + 768;        // 384

__device__ __forceinline__ float rcp_(float x) { return __builtin_amdgcn_rcpf(x); }

template<int CTRL>
__device__ __forceinline__ float dppmovf(float v) {
  return __int_as_float(__builtin_amdgcn_update_dpp(
      0, __float_as_int(v), CTRL, 0xF, 0xF, true));
}
// sum over 8 consecutive lanes, all-DPP (identical in all 8 lanes)
__device__ __forceinline__ float oct_sum(float v) {
  v += dppmovf<0xB1>(v);    // quad_perm xor1
  v += dppmovf<0x4E>(v);    // quad_perm xor2
  v += dppmovf<0x141>(v);   // row_half_mirror (combines the two quads)
  return v;
}
// full 64-lane sum, result in all lanes
__device__ __forceinline__ float wave_sum64(float v) {
  v += dppmovf<0xB1>(v);
  v += dppmovf<0x4E>(v);
  v += dppmovf<0x124>(v);   // row_ror:4
  v += dppmovf<0x128>(v);   // row_ror:8
  v += __shfl_xor(v, 16, 64);
  v += __shfl_xor(v, 32, 64);
  return v;
}

// ---------------- conv + relu ----------------
__global__ void kconv(const float* __restrict__ x, const float* __restrict__ cw,
                      const float* __restrict__ cb, float* __restrict__ t) {
  int idx = blockIdx.x * blockDim.x + threadIdx.x;
  if (idx >= 26214400) return;
  int w  = idx & 63;
  int h  = (idx >> 6) & 127;
  int d  = (idx >> 13) % 100;
  int o  = idx / 819200;
  float acc = cb[o];
#pragma unroll
  for (int i = 0; i < 4; ++i) {
    const float* xi = x + (((long long)i * 100 + d) * 130 + h) * 64 + w;
#pragma unroll
    for (int kh = 0; kh < 3; ++kh)
      acc = fmaf(cw[(o * 4 + i) * 3 + kh], xi[kh * 64], acc);
  }
  t[idx] = fmaxf(acc, 0.f);
}

// ---------------- big gram (init HOSVD): G = X X^T over fibers ----------------
#define GRAM_BLOCKS 240
template<int D, long long QQ, bool TRANS>
__global__ void kgram_big(const float* __restrict__ T, float* __restrict__ part,
                          int P) {
  constexpr int C = 64;
  constexpr int SUB = (D + 63) / 64;
  constexpr int DP = SUB * 64;
  __shared__ float tile[DP * (C + 1)];
  const int tid = threadIdx.x;                 // 256
  const int ta = tid >> 4, tb = tid & 15;
  float acc[SUB][SUB][4][4];
#pragma unroll
  for (int a = 0; a < SUB; ++a)
#pragma unroll
    for (int b = 0; b < SUB; ++b)
#pragma unroll
      for (int i = 0; i < 4; ++i)
#pragma unroll
        for (int j = 0; j < 4; ++j) acc[a][b][i][j] = 0.f;

  const long long nfib = (long long)P * QQ;
  const int nchunk = (int)(nfib / C);
  for (int ch = blockIdx.x; ch < nchunk; ch += gridDim.x) {
    const long long base = (long long)ch * C;
    __syncthreads();
    if (TRANS) {
      for (int e = tid; e < D * C; e += 256) {
        int a = e & 63, cc = e >> 6;
        tile[a * (C + 1) + cc] = T[base * D + e];
      }
    } else {
      for (int e = tid; e < DP * C; e += 256) {
        int a = e / C, cc = e % C;
        float v = 0.f;
        if (a < D) {
          long long f = base + cc;
          long long p = f / QQ, q = f - p * QQ;   // compile-time QQ
          v = T[(p * D + a) * QQ + q];
        }
        tile[a * (C + 1) + cc] = v;
      }
    }
    __syncthreads();
    for (int cc = 0; cc < C; ++cc) {
      float av[SUB][4], bv[SUB][4];
#pragma unroll
      for (int si = 0; si < SUB; ++si)
#pragma unroll
        for (int i = 0; i < 4; ++i) av[si][i] = tile[(si * 64 + ta * 4 + i) * (C + 1) + cc];
#pragma unroll
      for (int sj = 0; sj < SUB; ++sj)
#pragma unroll
        for (int j = 0; j < 4; ++j) bv[sj][j] = tile[(sj * 64 + tb * 4 + j) * (C + 1) + cc];
#pragma unroll
      for (int si = 0; si < SUB; ++si)
#pragma unroll
        for (int sj = 0; sj < SUB; ++sj)
#pragma unroll
          for (int i = 0; i < 4; ++i)
#pragma unroll
            for (int j = 0; j < 4; ++j)
              acc[si][sj][i][j] = fmaf(av[si][i], bv[sj][j], acc[si][sj][i][j]);
    }
  }
  float* pb = part + (long long)blockIdx.x * D * D;
  for (int si = 0; si < SUB; ++si)
    for (int i = 0; i < 4; ++i) {
      int a = si * 64 + ta * 4 + i;
      if (a >= D) continue;
      for (int sj = 0; sj < SUB; ++sj)
        for (int j = 0; j < 4; ++j) {
          int b = sj * 64 + tb * 4 + j;
          if (b >= D) continue;
          pb[a * D + b] = acc[si][sj][i][j];
        }
    }
}

__global__ void kreduce(const float* __restrict__ part, float* __restrict__ G, int DD) {
  int i = blockIdx.x * blockDim.x + threadIdx.x;
  if (i >= DD) return;
  float s = 0.f;
  for (int b = 0; b < GRAM_BLOCKS; ++b) s += part[(long long)b * DD + i];
  G[i] = s;
}

// ---------------- small gram (projected Y) ----------------
__global__ void kgram_small(const float* __restrict__ Y, float* __restrict__ G,
                            int P, int d, int Q) {
  int pair = blockIdx.x * blockDim.x + threadIdx.x;
  if (pair >= d * d) return;
  int a = pair / d, b = pair % d;
  float s = 0.f;
  for (int p = 0; p < P; ++p) {
    const float* ya = Y + ((long long)p * d + a) * Q;
    const float* yb = Y + ((long long)p * d + b) * Q;
    for (int q = 0; q < Q; ++q) s = fmaf(ya[q], yb[q], s);
  }
  G[pair] = s;
}

// ---------------- mode contraction: out[p,j,q] = sum_a F[a,j] in[p,a,q] ----------------
template<int R, long long QV>
__global__ void kcontract(const float* __restrict__ in, const float* __restrict__ F,
                          float* __restrict__ out, int P, int d) {
  long long total = (long long)P * QV;
  long long idx = (long long)blockIdx.x * blockDim.x + threadIdx.x;
  if (idx >= total) return;
  long long p = idx / QV, q = idx - p * QV;
  float acc[R];
#pragma unroll
  for (int j = 0; j < R; ++j) acc[j] = 0.f;
  const float* ip = in + (p * d) * QV + q;
  for (int a = 0; a < d; ++a) {
    float v = ip[(long long)a * QV];
#pragma unroll
    for (int j = 0; j < R; ++j) acc[j] = fmaf(F[a * R + j], v, acc[j]);
  }
  float* op = out + (p * R) * QV + q;
#pragma unroll
  for (int j = 0; j < R; ++j) op[(long long)j * QV] = acc[j];
}

// ---------------- eigh: top-r eigenvectors of symmetric G (n<=128) ----------------
#define EIG_THREADS 1024
#define EIG_WAVES 16

struct __align__(16) ESm {
  float ApkL[8256];              // packed-lower Householder columns (export)
  float ulb[128];                // pre-scaled u vector for the CURRENT step
  float wwf[128];                // w_pre vector
  float slv[8][516];             // invit solver: float4 {u0,u1,u2,-} per i
  float dd[128], ee[128], e2s[128], taus[128], scls[128];
  float vt[8][132];
  float lam[8];
  float red[16];                 // per-wave pu partials
  float sca[4];
};

template<int N, int RR>
__device__ void eig_body(ESm& S, const float* __restrict__ G, float* __restrict__ F) {
  constexpr int NP  = (N <= 32) ? 32 : ((N <= 64) ? 64 : 128);
  constexpr int QL  = NP / 8;          // floats per thread segment (4/8/16)
  constexpr int NC4 = QL / 4;          // float4 chunks per segment (1/2/4)
  const int tid  = threadIdx.x;
  const int lane = tid & 63, wv = tid >> 6;
  const int q    = tid & 7;            // 8 adjacent lanes share a row
  const int row  = tid >> 3;           // 0..127
  const bool actR = (row < N);
  const int l0 = q * QL;

  float4* ub4 = (float4*)S.ulb;
  float4* ww4 = (float4*)S.wwf;

  // ---- load: thread (row,q) owns A[row][l0 .. l0+QL) in VGPRs ----
  float Ar[QL];
#pragma unroll
  for (int j = 0; j < QL; ++j) Ar[j] = 0.f;
  if (actR) {
#pragma unroll
    for (int j = 0; j < QL; ++j) { int l = l0 + j; if (l < N) Ar[j] = G[row * N + l]; }
  }
  // ---- producer precompute for step 0: row 0 publishes scaled u + scalars ----
  if (row == 0) {
    const int t = 0;
    float aa = 0.f, nn = 0.f;
#pragma unroll
    for (int j = 0; j < QL; ++j) {
      int l = l0 + j;
      aa += (l == t + 1) ? Ar[j] : 0.f;
      float v = (l >= t + 2) ? Ar[j] : 0.f;
      nn = fmaf(v, v, nn);
    }
    aa = oct_sum(aa); nn = oct_sum(nn);
    float beta, tau_t, scl_t;
    if (nn == 0.f) { beta = aa; tau_t = 0.f; scl_t = 0.f; }
    else {
      float an = sqrtf(aa * aa + nn);
      beta = (aa >= 0.f) ? -an : an;
      tau_t = (beta - aa) * rcp_(beta);
      scl_t = rcp_(aa - beta);
    }
#pragma unroll
    for (int c = 0; c < NC4; ++c) {
      float o[4];
#pragma unroll
      for (int jj = 0; jj < 4; ++jj) {
        int j = 4 * c + jj, l = l0 + j;
        o[jj] = (l == t + 1) ? 1.f : ((l >= t + 2) ? Ar[j] * scl_t : 0.f);
      }
      ub4[(l0 >> 2) + c] = make_float4(o[0], o[1], o[2], o[3]);
    }
    if (q == 0) { S.ee[t] = beta; S.taus[t] = tau_t; S.scls[t] = scl_t; }
  }
  __syncthreads();

  // ---- Householder tridiagonalization (LAPACK slarfg conventions) ----
  const int wrow0 = wv << 3;           // 8 rows per wave
  for (int i = 0; i <= N - 3; ++i) {
    const bool wact = (wrow0 + 7 >= i + 1) && (wrow0 <= N - 1);
    float tau_i = 0.f, u_row = 0.f, w_pre = 0.f;
    float ul[QL];
    if (wact) {
      // read pre-scaled u segment + scalars (published before prev barrier B)
#pragma unroll
      for (int c = 0; c < NC4; ++c) {
        float4 t = ub4[(l0 >> 2) + c];
        ul[4*c] = t.x; ul[4*c+1] = t.y; ul[4*c+2] = t.z; ul[4*c+3] = t.w;
      }
      tau_i = S.taus[i];
      u_row = S.ulb[row];
      // symv partial + oct reduce
      float s = 0.f;
#pragma unroll
      for (int j = 0; j < QL; ++j) s = fmaf(Ar[j], ul[j], s);
      s = oct_sum(s);
      w_pre = (actR && row >= i + 1) ? tau_i * s : 0.f;
      if (q == 0) S.wwf[row] = w_pre;
      // pu partial: one per wave
      float p2 = (q == 0) ? w_pre * u_row : 0.f;
      p2 = wave_sum64(p2);
      if (lane == 0) S.red[wv] = p2;
    } else {
      if (q == 0) S.wwf[row] = 0.f;
      if (lane == 0) S.red[wv] = 0.f;
    }
    __syncthreads();                                   // A: wwf + red visible
    if (wact) {
      float4* r4 = (float4*)S.red;
      float pu = 0.f;
#pragma unroll
      for (int c = 0; c < 4; ++c) { float4 t = r4[c]; pu += ((t.x + t.y) + (t.z + t.w)); }
      float halfc = -0.5f * tau_i * pu;
      float w_row = fmaf(halfc, u_row, w_pre);
      float nu = -u_row, nw = -w_row;
#pragma unroll
      for (int c = 0; c < NC4; ++c) {
        float4 t = ww4[(l0 >> 2) + c];
        float wlq[4] = {t.x, t.y, t.z, t.w};
#pragma unroll
        for (int jj = 0; jj < 4; ++jj) {
          int j = 4 * c + jj;
          float w_l = fmaf(halfc, ul[j], wlq[jj]);
          Ar[j] = fmaf(nu, w_l, fmaf(nw, ul[j], Ar[j]));
        }
      }
      if (row == i + 1 && i < N - 3) {   // producer: publish step i+1's u + scalars
        const int t = i + 2;             // pivot index of next step (step i+1)
        float aa = 0.f, nn = 0.f;
#pragma unroll
        for (int j = 0; j < QL; ++j) {
          int l = l0 + j;
          aa += (l == t) ? Ar[j] : 0.f;
          float v = (l >= t + 1) ? Ar[j] : 0.f;
          nn = fmaf(v, v, nn);
        }
        aa = oct_sum(aa); nn = oct_sum(nn);
        float beta, tau_t, scl_t;
        if (nn == 0.f) { beta = aa; tau_t = 0.f; scl_t = 0.f; }
        else {
          float an = sqrtf(aa * aa + nn);
          beta = (aa >= 0.f) ? -an : an;
          tau_t = (beta - aa) * rcp_(beta);
          scl_t = rcp_(aa - beta);
        }
#pragma unroll
        for (int c = 0; c < NC4; ++c) {
          float o[4];
#pragma unroll
          for (int jj = 0; jj < 4; ++jj) {
            int j = 4 * c + jj, l = l0 + j;
            o[jj] = (l == t) ? 1.f : ((l >= t + 1) ? Ar[j] * scl_t : 0.f);
          }
          ub4[(l0 >> 2) + c] = make_float4(o[0], o[1], o[2], o[3]);
        }
        if (q == 0) { S.ee[i+1] = beta; S.taus[i+1] = tau_t; S.scls[i+1] = scl_t; }
      }
    }
    __syncthreads();                                   // B: ulb + scalars visible
  }

  // ---- export diag + packed-lower Householder columns + last off-diag ----
  if (actR) {
    int base = (row * (row - 1)) >> 1;
#pragma unroll
    for (int j = 0; j < QL; ++j) {
      int l = l0 + j;
      if (l == row) S.dd[row] = Ar[j];
      if (l < row)  S.ApkL[base + l] = Ar[j];
      if (row == N - 1 && l == N - 2) S.ee[N - 2] = Ar[j];
    }
  }
  __syncthreads();
  if (tid < N) S.e2s[tid] = (tid >= 1) ? S.ee[tid - 1] * S.ee[tid - 1] : 0.f;

  // ---- Gershgorin bounds + pivmin ----
  if (tid == 0) {
    float lo = 3.4e38f, hi = -3.4e38f, me2 = 0.f;
    for (int ii = 0; ii < N; ++ii) {
      float rad = 0.f;
      if (ii > 0) rad += fabsf(S.ee[ii - 1]);
      if (ii < N - 1) { rad += fabsf(S.ee[ii]); me2 = fmaxf(me2, S.ee[ii] * S.ee[ii]); }
      lo = fminf(lo, S.dd[ii] - rad);
      hi = fmaxf(hi, S.dd[ii] + rad);
    }
    float span = hi - lo;
    S.sca[0] = lo - 0.001f * span - 1e-20f;
    S.sca[1] = hi + 0.001f * span + 1e-20f;
    S.sca[2] = 1.1754944e-38f * fmaxf(1.f, me2);
  }
  __syncthreads();
  const float pivmin = S.sca[2];

  // ---- 33-way multisection: 32 threads per eigenvalue, 6 rounds ----
  {
    const int grp = tid >> 5, gt = tid & 31;
    if (grp < RR) {
      const int krank = N - 1 - grp;
      float lo = S.sca[0], hi = S.sca[1];
      for (int round = 0; round < 6; ++round) {
        float w = (hi - lo) * (1.f / 33.f);
        float sg = fmaf(w, (float)(gt + 1), lo);
        int cnt = 0;
        float qq = S.dd[0] - sg;
        if (qq < 0.f) cnt++;
#pragma unroll 4
        for (int ii = 1; ii < N; ++ii) {
          if (fabsf(qq) < pivmin) qq = -pivmin;
          qq = S.dd[ii] - sg - S.e2s[ii] * rcp_(qq);
          if (qq < 0.f) cnt++;
        }
        float nlo = (cnt <= krank) ? sg : lo;
        float nhi = (cnt >  krank) ? sg : hi;
        nlo = fmaxf(nlo, dppmovf<0xB1>(nlo));  nhi = fminf(nhi, dppmovf<0xB1>(nhi));
        nlo = fmaxf(nlo, dppmovf<0x4E>(nlo));  nhi = fminf(nhi, dppmovf<0x4E>(nhi));
        nlo = fmaxf(nlo, dppmovf<0x124>(nlo)); nhi = fminf(nhi, dppmovf<0x124>(nhi));
        nlo = fmaxf(nlo, dppmovf<0x128>(nlo)); nhi = fminf(nhi, dppmovf<0x128>(nhi));
        nlo = fmaxf(nlo, __shfl_xor(nlo, 16, 32));
        nhi = fminf(nhi, __shfl_xor(nhi, 16, 32));
        lo = fminf(nlo, nhi); hi = fmaxf(nlo, nhi);
      }
      if (gt == 0) S.lam[grp] = 0.5f * (lo + hi) * (1.f + (float)grp * 3e-7f);
    }
  }
  __syncthreads();

  // ---- inverse iteration: float4-packed solver, select pivoting ----
  if (tid < RR) {
    const int j = tid;
    float4* u4 = (float4*)&S.slv[j][0];
    float* vv = &S.vt[j][0];
    const float lj = S.lam[j];
    for (int k = 0; k < N; ++k) vv[k] = 1.f;
    float sc = 1.f;
    for (int itr = 0; itr < 3; ++itr) {
      float d = S.dd[0] - lj;
      float e = S.ee[0];
      float cv = vv[0] * sc;
#pragma unroll 4
      for (int i = 0; i < N - 1; ++i) {
        float bi = S.ee[i];
        float d1 = S.dd[i + 1] - lj;
        float e1 = (i + 1 < N - 1) ? S.ee[i + 1] : 0.f;
        float vnext = vv[i + 1] * sc;
        bool piv = (fabsf(d) >= fabsf(bi));
        float ad = d;
        if (piv && fabsf(ad) < pivmin) ad = (ad >= 0.f ? pivmin : -pivmin);
        float m   = piv ? (bi * rcp_(ad)) : (ad * rcp_(bi));
        float nu0 = piv ? ad : bi;
        float nu1 = piv ? e  : d1;
        float nu2 = piv ? 0.f : e1;
        u4[i] = make_float4(nu0, nu1, nu2, 0.f);
        float nd = piv ? (d1 - m * e) : (e - m * d1);
        float ne = piv ? e1 : (-m * e1);
        vv[i] = piv ? cv : vnext;
        cv = piv ? (vnext - m * cv) : (cv - m * vnext);
        d = nd; e = ne;
      }
      if (fabsf(d) < pivmin) d = (d >= 0.f ? pivmin : -pivmin);
      float vi2 = cv * rcp_(d);
      vv[N - 1] = vi2;
      float mx = fabsf(vi2);
      float4 uN2 = u4[N - 2];
      float vi1 = (vv[N - 2] - uN2.y * vi2) * rcp_(uN2.x);
      vv[N - 2] = vi1;
      mx = fmaxf(mx, fabsf(vi1));
#pragma unroll 4
      for (int i = N - 3; i >= 0; --i) {
        float4 u = u4[i];
        float t = (vv[i] - u.y * vi1 - u.z * vi2) * rcp_(u.x);
        vv[i] = t;
        mx = fmaxf(mx, fabsf(t));
        vi2 = vi1; vi1 = t;
      }
      sc = rcp_(fmaxf(mx, 1e-30f));
    }
    for (int k = 0; k < N; ++k) vv[k] *= sc;   // final normalize (overflow guard)
  }
  __syncthreads();

  // ---- MGS orthonormalization: single wave, DPP reductions ----
  if (wv == 0) {
    const int k1 = lane, k2 = lane + 64;
    for (int j = 0; j < RR; ++j) {
      float vj1 = (k1 < N) ? S.vt[j][k1] : 0.f;
      float vj2 = (k2 < N) ? S.vt[j][k2] : 0.f;
      for (int i2 = 0; i2 < j; ++i2) {
        float a1 = (k1 < N) ? S.vt[i2][k1] : 0.f;
        float a2 = (k2 < N) ? S.vt[i2][k2] : 0.f;
        float p = wave_sum64(vj1 * a1 + vj2 * a2);
        vj1 -= p * a1; vj2 -= p * a2;
      }
      float nn2 = wave_sum64(vj1 * vj1 + vj2 * vj2);
      float inv = rsqrtf(fmaxf(nn2, 1e-33f));
      vj1 *= inv; vj2 *= inv;
      if (k1 < N) S.vt[j][k1] = vj1;
      if (k2 < N) S.vt[j][k2] = vj2;
    }
  }
  __syncthreads();

  // ---- back-transform: v carried in registers; DPP reductions ----
  for (int vec = wv; vec < RR; vec += EIG_WAVES) {
    float* v = &S.vt[vec][0];
    const int k1 = lane, k2 = lane + 64;
    float v1 = (k1 < N) ? v[k1] : 0.f;
    float v2 = (k2 < N) ? v[k2] : 0.f;
    for (int h = N - 3; h >= 0; --h) {
      const float sh = S.scls[h];
      float uk1 = 0.f, uk2 = 0.f;
      if (k1 > h && k1 < N)
        uk1 = (k1 == h + 1) ? 1.f : S.ApkL[((k1 * (k1 - 1)) >> 1) + h] * sh;
      if (k2 > h && k2 < N)
        uk2 = (k2 == h + 1) ? 1.f : S.ApkL[((k2 * (k2 - 1)) >> 1) + h] * sh;
      float dp = wave_sum64(uk1 * v1 + uk2 * v2);
      float c = S.taus[h] * dp;
      v1 -= c * uk1; v2 -= c * uk2;
    }
    if (k1 < N) v[k1] = v1;
    if (k2 < N) v[k2] = v2;
  }
  __syncthreads();

  // ---- canonical sign (max-|component| positive) + write F (N x RR) ----
  for (int vec = wv; vec < RR; vec += EIG_WAVES) {
    float* v = &S.vt[vec][0];
    float ma = -1.f; int mi = 0x7fffffff;
    for (int k = lane; k < N; k += 64) {
      float a = fabsf(v[k]);
      if (a > ma || (a == ma && k < mi)) { ma = a; mi = k; }
    }
#pragma unroll
    for (int off = 32; off > 0; off >>= 1) {
      float oa = __shfl_down(ma, off, 64);
      int oi = __shfl_down(mi, off, 64);
      if (oa > ma || (oa == ma && oi < mi)) { ma = oa; mi = oi; }
    }
    mi = __shfl(mi, 0, 64);
    float sg = (v[mi] < 0.f) ? -1.f : 1.f;
    for (int k = lane; k < N; k += 64) F[k * RR + vec] = sg * v[k];
  }
}

__global__ __launch_bounds__(EIG_THREADS, 1)
void keigh_init(const float* G0, float* F0, const float* G1, float* F1,
                const float* G2, float* F2, const float* G3, float* F3) {
  __shared__ ESm S;
  if (blockIdx.x == 0)      eig_body<32, 8>(S, G0, F0);
  else if (blockIdx.x == 1) eig_body<100, 6>(S, G1, F1);
  else if (blockIdx.x == 2) eig_body<128, 6>(S, G2, F2);
  else                      eig_body<64, 6>(S, G3, F3);
}

template<int N, int RR>
__global__ __launch_bounds__(EIG_THREADS, 1)
void keigh_one(const float* __restrict__ G, float* __restrict__ F) {
  __shared__ ESm S;
  eig_body<N, RR>(S, G, F);
}

// ---------------------------------------------------------------------------
extern "C" void kernel_launch(void* const* d_in, const int* in_sizes, int n_in,
                              void* d_out, int out_size, void* d_ws, size_t ws_size,
                              hipStream_t stream) {
  (void)in_sizes; (void)n_in; (void)out_size; (void)ws_size;
  const float* x  = (const float*)d_in[0];
  const float* cw = (const float*)d_in[1];
  const float* cb = (const float*)d_in[2];
  float* out = (float*)d_out;
  float* ws  = (float*)d_ws;

  float* T    = ws + OFF_T;
  float* TC   = ws + OFF_TC;
  float* TB   = ws + OFF_TB;
  float* PART = ws + OFF_PART;
  float* TD0a = ws + OFF_TD0a;
  float* TD0b = ws + OFF_TD0b;
  float* TD   = ws + OFF_TD;
  float* G0   = ws + OFF_G0;
  float* G1   = ws + OFF_G1;
  float* G2   = ws + OFF_G2;
  float* G3   = ws + OFF_G3;
  float* F0   = ws + OFF_F0;
  float* F1   = ws + OFF_F1;
  float* F2   = ws + OFF_F2;
  float* F3   = ws + OFF_F3;

  kconv<<<(26214400 + 255) / 256, 256, 0, stream>>>(x, cw, cb, T);

  // ---- HOSVD init: 4 grams, then one batched 4-block eigh ----
  kgram_big<32, 819200, false><<<GRAM_BLOCKS, 256, 0, stream>>>(T, PART, 1);
  kreduce<<<4, 256, 0, stream>>>(PART, G0, 1024);
  kgram_big<100, 8192, false><<<GRAM_BLOCKS, 256, 0, stream>>>(T, PART, 32);
  kreduce<<<40, 256, 0, stream>>>(PART, G1, 10000);
  kgram_big<128, 64, false><<<GRAM_BLOCKS, 256, 0, stream>>>(T, PART, 3200);
  kreduce<<<64, 256, 0, stream>>>(PART, G2, 16384);
  kgram_big<64, 1, true><<<GRAM_BLOCKS, 256, 0, stream>>>(T, PART, 409600);
  kreduce<<<16, 256, 0, stream>>>(PART, G3, 4096);

  keigh_init<<<4, EIG_THREADS, 0, stream>>>(G0, F0, G1, F1, G2, F2, G3, F3);

  // ---- HOOI sweeps ----
  for (int sweep = 0; sweep < 5; ++sweep) {
    // mode 0: Y = T x1 F1 x2 F2 x3 F3 -> (32,6,6,6)
    kcontract<6, 8192><<<1024, 256, 0, stream>>>(T, F1, TB, 32, 100);
    kcontract<6, 64><<<48, 256, 0, stream>>>(TB, F2, TD0a, 192, 128);
    kcontract<6, 1><<<5, 256, 0, stream>>>(TD0a, F3, TD0b, 1152, 64);
    kgram_small<<<4, 256, 0, stream>>>(TD0b, G0, 1, 32, 216);
    keigh_one<32, 8><<<1, EIG_THREADS, 0, stream>>>(G0, F0);
    // TC = T x0 F0 (reused by modes 1,2,3 and the final core)
    kcontract<8, 819200><<<3200, 256, 0, stream>>>(T, F0, TC, 1, 32);
    // mode 1
    kcontract<6, 64><<<200, 256, 0, stream>>>(TC, F2, TB, 800, 128);
    kcontract<6, 1><<<19, 256, 0, stream>>>(TB, F3, TD, 4800, 64);
    kgram_small<<<40, 256, 0, stream>>>(TD, G0, 8, 100, 36);
    keigh_one<100, 6><<<1, EIG_THREADS, 0, stream>>>(G0, F1);
    // mode 2 (TB = TC x1 F1 also reused by mode 3)
    kcontract<6, 8192><<<256, 256, 0, stream>>>(TC, F1, TB, 8, 100);
    kcontract<6, 1><<<24, 256, 0, stream>>>(TB, F3, TD, 6144, 64);
    kgram_small<<<64, 256, 0, stream>>>(TD, G0, 48, 128, 6);
    keigh_one<128, 6><<<1, EIG_THREADS, 0, stream>>>(G0, F2);
    // mode 3 (reuses TB from mode 2)
    kcontract<6, 64><<<12, 256, 0, stream>>>(TB, F2, TD, 48, 128);
    kgram_small<<<16, 256, 0, stream>>>(TD, G0, 288, 64, 1);
    keigh_one<64, 6><<<1, EIG_THREADS, 0, stream>>>(G0, F3);
  }

  // ---- core = (TC) x1 F1 x2 F2 x3 F3 -> (8,6,6,6) ----
  kcontract<6, 8192><<<256, 256, 0, stream>>>(TC, F1, TB, 8, 100);
  kcontract<6, 64><<<12, 256, 0, stream>>>(TB, F2, TD, 48, 128);
  kcontract<6, 1><<<2, 256, 0, stream>>>(TD, F3, out, 288, 64);
}